// Round 12
// baseline (255.217 us; speedup 1.0000x reference)
//
#include <hip/hip_runtime.h>

// BusStopPredictor: 2x SAGEConv(mean) + BN(eval) + ReLU, then Linear(64->1).
// N=50000 nodes, E=800000 edges, 32 -> 64 -> 64 -> 1.
//
// Round 1: dst-sorted CSR + per-node gather (no float atomics): 1251 -> 374us.
// Round 2: node GEMMs 16-lanes-per-node: 374 -> 337us.
// Round 4: LDS weights + 4 nodes/thread; node1 full-unroll spilled: -> 371us.
// Round 5: unroll capped at 4 + gathers 2 edge-slots/node: -> 284us.
// Round 6: XCD-partitioned fill FAILED (chunk-claim barriers killed MLP).
// Round 7/9: uint16 csr + 4-slot gathers: -> 272us.
// Round 10: slice x range fill + NT: 269us (scatter write-back is structural).
// Round 11: two-pass LDS radix CSR build (binA bins (dst<<16|src) into 196
//          256-node buckets; binB builds deg/base/csr per bucket entirely in
//          LDS, each csr line written once by one block): 269 -> 214us.
//          Replaced k_deg + 3 scans + fill. Top-5 now 100% harness poison
//          fills; all our kernels < 45us.
// Round 12: (a) fuse gather into node kernels (agg lives in LDS, never in
//          global): kills 25.6MB/layer round-trip + 2 dispatches.
//          (b) h stored as bf16 (RNE): halves gather64's 204.8MB random row
//          reads, h write, and node2 root reads. 5 dispatches total.

constexpr int NN = 50000;
constexpr int NE = 800000;
constexpr int NBLK = (NN + 63) / 64;    // 782 blocks, 64 nodes each
constexpr float BN_EPS = 1e-5f;

constexpr int NBUCK = 196;              // buckets of 256 nodes (dst>>8)
constexpr int BCAP  = 8192;             // per-bucket capacity (avg 4082, max ~4350)
constexpr int APB   = 2048;             // edges per pass-A block
constexpr int NAB   = (NE + APB - 1) / APB;  // 391

// fp32 -> bf16, round-to-nearest-even
__device__ __forceinline__ unsigned short f2bf(float f) {
    union { float f; unsigned int u; } c; c.f = f;
    unsigned int lsb = (c.u >> 16) & 1u;
    c.u += 0x7fffu + lsb;
    return (unsigned short)(c.u >> 16);
}

// ---------------- pass A: bin edges by dst>>8 ----------------
__global__ __launch_bounds__(256) void k_binA(const int* __restrict__ ei,
                                              int* __restrict__ cursor,
                                              unsigned int* __restrict__ region) {
    __shared__ int lcnt[NBUCK];
    __shared__ int gb[NBUCK];
    int tid = threadIdx.x;
    for (int i = tid; i < NBUCK; i += 256) lcnt[i] = 0;
    __syncthreads();
    int e0 = blockIdx.x * APB;
    unsigned int pk[8];
    int bk[8], rk[8];
#pragma unroll
    for (int i = 0; i < 8; i++) {
        int e = e0 + i * 256 + tid;
        bk[i] = -1;
        if (e < NE) {
            int s = ei[e];
            int d = ei[NE + e];
            pk[i] = ((unsigned int)d << 16) | (unsigned int)s;
            bk[i] = d >> 8;
            rk[i] = atomicAdd(&lcnt[bk[i]], 1);
        }
    }
    __syncthreads();
    if (tid < NBUCK && lcnt[tid] > 0) gb[tid] = atomicAdd(&cursor[tid], lcnt[tid]);
    __syncthreads();
#pragma unroll
    for (int i = 0; i < 8; i++) {
        if (bk[i] >= 0) region[bk[i] * BCAP + gb[bk[i]] + rk[i]] = pk[i];
    }
}

// ---------------- pass B: build csr segment per bucket ----------------
__global__ __launch_bounds__(256) void k_binB(const int* __restrict__ cursor,
                                              const unsigned int* __restrict__ region,
                                              int* __restrict__ deg_i,
                                              int* __restrict__ base,
                                              unsigned short* __restrict__ csr16) {
    __shared__ unsigned int stg[BCAP];   // 32KB
    __shared__ int lc[256], cur[256], sctmp[256];
    int tid = threadIdx.x;
    int b = blockIdx.x;

    // exclusive scan of all bucket counts -> my csr base B0
    int cntt = (tid < NBUCK) ? cursor[tid] : 0;
    sctmp[tid] = cntt;
    __syncthreads();
    for (int off = 1; off < 256; off <<= 1) {
        int t = (tid >= off) ? sctmp[tid - off] : 0;
        __syncthreads();
        sctmp[tid] += t;
        __syncthreads();
    }
    int B0 = (b == 0) ? 0 : sctmp[b - 1];
    int mycnt = cursor[b];

    for (int k = tid; k < mycnt; k += 256) stg[k] = region[b * BCAP + k];
    lc[tid] = 0;
    __syncthreads();

    int node0 = b << 8;
    for (int k = tid; k < mycnt; k += 256) {
        int local = (int)(stg[k] >> 16) - node0;
        atomicAdd(&lc[local], 1);
    }
    __syncthreads();

    int myc = lc[tid];
    sctmp[tid] = myc;
    __syncthreads();
    for (int off = 1; off < 256; off <<= 1) {
        int t = (tid >= off) ? sctmp[tid - off] : 0;
        __syncthreads();
        sctmp[tid] += t;
        __syncthreads();
    }
    int myoff = sctmp[tid] - myc;
    cur[tid] = myoff;
    int n = node0 + tid;
    if (n < NN) {
        deg_i[n] = myc;
        base[n] = B0 + myoff + myc;   // row_end (gather contract)
    }
    __syncthreads();

    for (int k = tid; k < mycnt; k += 256) {
        unsigned int p = stg[k];
        int local = (int)(p >> 16) - node0;
        int pos = atomicAdd(&cur[local], 1);
        csr16[B0 + pos] = (unsigned short)(p & 0xffffu);
    }
}

// ---------------- fused layer 1: gather(x) + GEMM + BN + ReLU -> h (bf16) ----
// Block = 64 nodes. LDS: weights 16KB + agg tile 8KB.
// Gather: 2 passes x (32 nodes x 8 lanes), lane owns 4 ch, serial edge walk.
// Compute: 16 lanes/node x 4 out-ch, 4 nodes/thread (r4/r5 proven mapping).
__global__ __launch_bounds__(256) void k_fused1(
    const float* __restrict__ x,
    const unsigned short* __restrict__ csr16,
    const int* __restrict__ base, const int* __restrict__ deg_i,
    const float* __restrict__ W1l, const float* __restrict__ b1l,
    const float* __restrict__ W1r,
    const float* __restrict__ g1, const float* __restrict__ bb1,
    const float* __restrict__ m1, const float* __restrict__ v1,
    unsigned short* __restrict__ h) {
    __shared__ float wlds[32 * 128];   // 16KB: row k = W1l[k][0:64] | W1r[k][0:64]
    __shared__ float aggs[64 * 32];    // 8KB
    int tid = threadIdx.x;
    {
        const float4* l4 = (const float4*)W1l;   // 512 float4
        const float4* r4 = (const float4*)W1r;
        float4* s4 = (float4*)wlds;
#pragma unroll
        for (int i = 0; i < 2; i++) {
            int idx = tid + i * 256;
            int k = idx >> 4, c = idx & 15;
            s4[k * 32 + c] = l4[idx];
            s4[k * 32 + 16 + c] = r4[idx];
        }
    }
    int nb0 = blockIdx.x * 64;
#pragma unroll
    for (int g = 0; g < 2; g++) {
        int nl = g * 32 + (tid >> 3);
        int c4 = (tid & 7) << 2;
        int nc = min(nb0 + nl, NN - 1);
        int end = base[nc];
        int st = end - deg_i[nc];
        float4 acc = make_float4(0.f, 0.f, 0.f, 0.f);
        for (int e = st; e < end; e++) {
            int s = csr16[e];
            float4 v = *(const float4*)(x + (size_t)s * 32 + c4);
            acc.x += v.x; acc.y += v.y; acc.z += v.z; acc.w += v.w;
        }
        *(float4*)&aggs[nl * 32 + c4] = acc;
    }
    __syncthreads();

    int lg = tid & 15, o4 = lg << 2;
    int nbase = nb0 + (tid >> 4) * 4;
    if (nbase >= NN) return;

    float4 acc[4];
    float di[4];
    int nj[4], njl[4];
#pragma unroll
    for (int j = 0; j < 4; j++) {
        acc[j] = make_float4(0.f, 0.f, 0.f, 0.f);
        nj[j] = min(nbase + j, NN - 1);
        njl[j] = nj[j] - nb0;
        di[j] = 1.0f / fmaxf((float)deg_i[nj[j]], 1.0f);
    }

#pragma unroll 4
    for (int i4 = 0; i4 < 32; i4 += 4) {
        float4 wl[4], wr[4];
#pragma unroll
        for (int k = 0; k < 4; k++) {
            wl[k] = *(const float4*)&wlds[(i4 + k) * 128 + o4];
            wr[k] = *(const float4*)&wlds[(i4 + k) * 128 + 64 + o4];
        }
#pragma unroll
        for (int j = 0; j < 4; j++) {
            float4 a4 = *(const float4*)&aggs[njl[j] * 32 + i4];
            float4 x4 = *(const float4*)(x + (size_t)nj[j] * 32 + i4);
            float av[4] = {a4.x * di[j], a4.y * di[j], a4.z * di[j], a4.w * di[j]};
            float xv[4] = {x4.x, x4.y, x4.z, x4.w};
#pragma unroll
            for (int k = 0; k < 4; k++) {
                acc[j].x += av[k] * wl[k].x + xv[k] * wr[k].x;
                acc[j].y += av[k] * wl[k].y + xv[k] * wr[k].y;
                acc[j].z += av[k] * wl[k].z + xv[k] * wr[k].z;
                acc[j].w += av[k] * wl[k].w + xv[k] * wr[k].w;
            }
        }
    }

    float4 bl = *(const float4*)(b1l + o4);
    float4 gg = *(const float4*)(g1 + o4);
    float4 bb = *(const float4*)(bb1 + o4);
    float4 mm = *(const float4*)(m1 + o4);
    float4 vv = *(const float4*)(v1 + o4);
    float4 sc;
    sc.x = gg.x * rsqrtf(vv.x + BN_EPS);
    sc.y = gg.y * rsqrtf(vv.y + BN_EPS);
    sc.z = gg.z * rsqrtf(vv.z + BN_EPS);
    sc.w = gg.w * rsqrtf(vv.w + BN_EPS);
#pragma unroll
    for (int j = 0; j < 4; j++) {
        if (nbase + j >= NN) break;
        ushort4 r;
        r.x = f2bf(fmaxf((acc[j].x + bl.x - mm.x) * sc.x + bb.x, 0.0f));
        r.y = f2bf(fmaxf((acc[j].y + bl.y - mm.y) * sc.y + bb.y, 0.0f));
        r.z = f2bf(fmaxf((acc[j].z + bl.z - mm.z) * sc.z + bb.z, 0.0f));
        r.w = f2bf(fmaxf((acc[j].w + bl.w - mm.w) * sc.w + bb.w, 0.0f));
        *(ushort4*)(h + (size_t)(nbase + j) * 64 + o4) = r;
    }
}

// ---------------- fused layer 2: gather(h bf16) + GEMM + BN + ReLU + lin ----
// Block = 64 nodes. LDS: weights 32KB + agg tile 16KB (48KB -> 3 blocks/CU).
// Gather: 2 passes x (32 nodes x 8 lanes), lane owns 8 ch (uint4 = 8 bf16).
__global__ __launch_bounds__(256) void k_fused2(
    const unsigned short* __restrict__ h,
    const unsigned short* __restrict__ csr16,
    const int* __restrict__ base, const int* __restrict__ deg_i,
    const float* __restrict__ W2l, const float* __restrict__ b2l,
    const float* __restrict__ W2r,
    const float* __restrict__ g2, const float* __restrict__ bb2,
    const float* __restrict__ m2, const float* __restrict__ v2,
    const float* __restrict__ Wlin, const float* __restrict__ blin,
    float* __restrict__ out) {
    __shared__ float wlds[64 * 128];   // 32KB
    __shared__ float aggs[64 * 64];    // 16KB
    int tid = threadIdx.x;
    {
        const float4* l4 = (const float4*)W2l;   // 1024 float4
        const float4* r4 = (const float4*)W2r;
        float4* s4 = (float4*)wlds;
#pragma unroll
        for (int i = 0; i < 4; i++) {
            int idx = tid + i * 256;
            int k = idx >> 4, c = idx & 15;
            s4[k * 32 + c] = l4[idx];
            s4[k * 32 + 16 + c] = r4[idx];
        }
    }
    int nb0 = blockIdx.x * 64;
#pragma unroll
    for (int g = 0; g < 2; g++) {
        int nl = g * 32 + (tid >> 3);
        int c8 = (tid & 7) << 3;
        int nc = min(nb0 + nl, NN - 1);
        int end = base[nc];
        int st = end - deg_i[nc];
        float a0 = 0.f, a1 = 0.f, a2 = 0.f, a3 = 0.f;
        float a4 = 0.f, a5 = 0.f, a6 = 0.f, a7 = 0.f;
        for (int e = st; e < end; e++) {
            int s = csr16[e];
            uint4 v = *(const uint4*)(h + (size_t)s * 64 + c8);
            a0 += __uint_as_float(v.x << 16);
            a1 += __uint_as_float(v.x & 0xffff0000u);
            a2 += __uint_as_float(v.y << 16);
            a3 += __uint_as_float(v.y & 0xffff0000u);
            a4 += __uint_as_float(v.z << 16);
            a5 += __uint_as_float(v.z & 0xffff0000u);
            a6 += __uint_as_float(v.w << 16);
            a7 += __uint_as_float(v.w & 0xffff0000u);
        }
        *(float4*)&aggs[nl * 64 + c8]     = make_float4(a0, a1, a2, a3);
        *(float4*)&aggs[nl * 64 + c8 + 4] = make_float4(a4, a5, a6, a7);
    }
    __syncthreads();

    int lg = tid & 15, o4 = lg << 2;
    int nbase = nb0 + (tid >> 4) * 4;
    if (nbase >= NN) return;

    float4 acc[4];
    float di[4];
    int nj[4], njl[4];
#pragma unroll
    for (int j = 0; j < 4; j++) {
        acc[j] = make_float4(0.f, 0.f, 0.f, 0.f);
        nj[j] = min(nbase + j, NN - 1);
        njl[j] = nj[j] - nb0;
        di[j] = 1.0f / fmaxf((float)deg_i[nj[j]], 1.0f);
    }

#pragma unroll 4
    for (int i4 = 0; i4 < 64; i4 += 4) {
        float4 wl[4], wr[4];
#pragma unroll
        for (int k = 0; k < 4; k++) {
            wl[k] = *(const float4*)&wlds[(i4 + k) * 128 + o4];
            wr[k] = *(const float4*)&wlds[(i4 + k) * 128 + 64 + o4];
        }
#pragma unroll
        for (int j = 0; j < 4; j++) {
            float4 ag = *(const float4*)&aggs[njl[j] * 64 + i4];
            uint2 hu = *(const uint2*)(h + (size_t)nj[j] * 64 + i4);
            float av[4] = {ag.x * di[j], ag.y * di[j], ag.z * di[j], ag.w * di[j]};
            float hv[4];
            hv[0] = __uint_as_float(hu.x << 16);
            hv[1] = __uint_as_float(hu.x & 0xffff0000u);
            hv[2] = __uint_as_float(hu.y << 16);
            hv[3] = __uint_as_float(hu.y & 0xffff0000u);
#pragma unroll
            for (int k = 0; k < 4; k++) {
                acc[j].x += av[k] * wl[k].x + hv[k] * wr[k].x;
                acc[j].y += av[k] * wl[k].y + hv[k] * wr[k].y;
                acc[j].z += av[k] * wl[k].z + hv[k] * wr[k].z;
                acc[j].w += av[k] * wl[k].w + hv[k] * wr[k].w;
            }
        }
    }

    float4 bl = *(const float4*)(b2l + o4);
    float4 gg = *(const float4*)(g2 + o4);
    float4 bb = *(const float4*)(bb2 + o4);
    float4 mm = *(const float4*)(m2 + o4);
    float4 vv = *(const float4*)(v2 + o4);
    float4 wo = *(const float4*)(Wlin + o4);
    float blin0 = blin[0];
    float4 sc;
    sc.x = gg.x * rsqrtf(vv.x + BN_EPS);
    sc.y = gg.y * rsqrtf(vv.y + BN_EPS);
    sc.z = gg.z * rsqrtf(vv.z + BN_EPS);
    sc.w = gg.w * rsqrtf(vv.w + BN_EPS);
#pragma unroll
    for (int j = 0; j < 4; j++) {
        float vx = fmaxf((acc[j].x + bl.x - mm.x) * sc.x + bb.x, 0.0f);
        float vy = fmaxf((acc[j].y + bl.y - mm.y) * sc.y + bb.y, 0.0f);
        float vz = fmaxf((acc[j].z + bl.z - mm.z) * sc.z + bb.z, 0.0f);
        float vw = fmaxf((acc[j].w + bl.w - mm.w) * sc.w + bb.w, 0.0f);
        float part = vx * wo.x + vy * wo.y + vz * wo.z + vw * wo.w;
#pragma unroll
        for (int m = 1; m < 16; m <<= 1) part += __shfl_xor(part, m, 64);
        if (lg == 0 && nbase + j < NN) out[nbase + j] = part + blin0;
    }
}

extern "C" void kernel_launch(void* const* d_in, const int* in_sizes, int n_in,
                              void* d_out, int out_size, void* d_ws, size_t ws_size,
                              hipStream_t stream) {
    const float* x    = (const float*)d_in[0];
    const int*   ei   = (const int*)d_in[1];
    const float* W1l  = (const float*)d_in[2];
    const float* b1l  = (const float*)d_in[3];
    const float* W1r  = (const float*)d_in[4];
    const float* g1   = (const float*)d_in[5];
    const float* bb1  = (const float*)d_in[6];
    const float* m1   = (const float*)d_in[7];
    const float* v1   = (const float*)d_in[8];
    const float* W2l  = (const float*)d_in[9];
    const float* b2l  = (const float*)d_in[10];
    const float* W2r  = (const float*)d_in[11];
    const float* g2   = (const float*)d_in[12];
    const float* bb2  = (const float*)d_in[13];
    const float* m2   = (const float*)d_in[14];
    const float* v2   = (const float*)d_in[15];
    const float* Wlin = (const float*)d_in[16];
    const float* blin = (const float*)d_in[17];
    float* out = (float*)d_out;

    // ws layout:
    //   cursor  int[256]          per-bucket claim cursors (only [0,196) used)
    //   region  u32[196*8192]     binned packed edges (6.4MB)
    //   deg_i   int[N]            degree per dst node (written by pass B)
    //   base    int[N]            row_end per node (written by pass B)
    //   csr16   ushort[E]         src indices sorted by dst
    //   h       bf16[64N]         layer-1 output (6.4MB)
    int* cursor = (int*)d_ws;
    unsigned int* region = (unsigned int*)(cursor + 256);
    int* deg_i = (int*)(region + (size_t)NBUCK * BCAP);
    int* base  = deg_i + NN;
    unsigned short* csr16 = (unsigned short*)(base + NN);
    unsigned short* h = csr16 + NE;

    // only the bucket cursors need zeroing (1KB)
    hipMemsetAsync(cursor, 0, 256 * sizeof(int), stream);

    k_binA<<<NAB, 256, 0, stream>>>(ei, cursor, region);
    k_binB<<<NBUCK, 256, 0, stream>>>(cursor, region, deg_i, base, csr16);
    k_fused1<<<NBLK, 256, 0, stream>>>(x, csr16, base, deg_i, W1l, b1l, W1r,
                                       g1, bb1, m1, v1, h);
    k_fused2<<<NBLK, 256, 0, stream>>>(h, csr16, base, deg_i, W2l, b2l, W2r,
                                       g2, bb2, m2, v2, Wlin, blin, out);
}

// Round 14
// 205.291 us; speedup vs baseline: 1.2432x; 1.2432x over previous
//
#include <hip/hip_runtime.h>

// BusStopPredictor: 2x SAGEConv(mean) + BN(eval) + ReLU, then Linear(64->1).
// N=50000 nodes, E=800000 edges, 32 -> 64 -> 64 -> 1.
//
// Round 1: dst-sorted CSR + per-node gather (no float atomics): 1251 -> 374us.
// Round 2: node GEMMs 16-lanes-per-node: 374 -> 337us.
// Round 4: LDS weights + 4 nodes/thread; node1 full-unroll spilled: -> 371us.
// Round 5: unroll capped at 4 + gathers 2 edge-slots/node: -> 284us.
// Round 6: XCD-partitioned fill FAILED (chunk-claim barriers killed MLP).
// Round 7/9: uint16 csr + 4-slot gathers: -> 272us.
// Round 10: slice x range fill + NT: 269us (scatter write-back is structural).
// Round 11: two-pass LDS radix CSR build: 269 -> 214us (best).
// Round 12: fuse gather+node FAILED (255us): 48KB LDS -> 18% occupancy, and
//          fused gather degraded to 8 lanes/node x 1 slot = 16-deep serial
//          chain. But bf16-h half WORKED: FETCH halved, absmax 0.004 ok.
// Round 13: revert to round-11 pipeline, keep ONLY bf16-h: node1 packs bf16,
//          gather64 reads 128B/edge-row (was 256B), node2 unpacks roots.
// Round 14: resubmit unchanged (round-13 bench hit GPUAcquisitionTimeout).

constexpr int NN = 50000;
constexpr int NE = 800000;
constexpr int NBLK = (NN + 63) / 64;    // 782 blocks, 64 nodes each
constexpr float BN_EPS = 1e-5f;

constexpr int NBUCK = 196;              // buckets of 256 nodes (dst>>8)
constexpr int BCAP  = 8192;             // per-bucket capacity (avg 4082)
constexpr int APB   = 2048;             // edges per pass-A block
constexpr int NAB   = (NE + APB - 1) / APB;  // 391

// fp32 -> bf16, round-to-nearest-even
__device__ __forceinline__ unsigned short f2bf(float f) {
    union { float f; unsigned int u; } c; c.f = f;
    unsigned int lsb = (c.u >> 16) & 1u;
    c.u += 0x7fffu + lsb;
    return (unsigned short)(c.u >> 16);
}

// ---------------- pass A: bin edges by dst>>8 ----------------
__global__ __launch_bounds__(256) void k_binA(const int* __restrict__ ei,
                                              int* __restrict__ cursor,
                                              unsigned int* __restrict__ region) {
    __shared__ int lcnt[NBUCK];
    __shared__ int gb[NBUCK];
    int tid = threadIdx.x;
    for (int i = tid; i < NBUCK; i += 256) lcnt[i] = 0;
    __syncthreads();
    int e0 = blockIdx.x * APB;
    unsigned int pk[8];
    int bk[8], rk[8];
#pragma unroll
    for (int i = 0; i < 8; i++) {
        int e = e0 + i * 256 + tid;
        bk[i] = -1;
        if (e < NE) {
            int s = ei[e];
            int d = ei[NE + e];
            pk[i] = ((unsigned int)d << 16) | (unsigned int)s;
            bk[i] = d >> 8;
            rk[i] = atomicAdd(&lcnt[bk[i]], 1);
        }
    }
    __syncthreads();
    if (tid < NBUCK && lcnt[tid] > 0) gb[tid] = atomicAdd(&cursor[tid], lcnt[tid]);
    __syncthreads();
#pragma unroll
    for (int i = 0; i < 8; i++) {
        if (bk[i] >= 0) region[bk[i] * BCAP + gb[bk[i]] + rk[i]] = pk[i];
    }
}

// ---------------- pass B: build csr segment per bucket ----------------
__global__ __launch_bounds__(256) void k_binB(const int* __restrict__ cursor,
                                              const unsigned int* __restrict__ region,
                                              int* __restrict__ deg_i,
                                              int* __restrict__ base,
                                              unsigned short* __restrict__ csr16) {
    __shared__ unsigned int stg[BCAP];   // 32KB
    __shared__ int lc[256], cur[256], sctmp[256];
    int tid = threadIdx.x;
    int b = blockIdx.x;

    int cntt = (tid < NBUCK) ? cursor[tid] : 0;
    sctmp[tid] = cntt;
    __syncthreads();
    for (int off = 1; off < 256; off <<= 1) {
        int t = (tid >= off) ? sctmp[tid - off] : 0;
        __syncthreads();
        sctmp[tid] += t;
        __syncthreads();
    }
    int B0 = (b == 0) ? 0 : sctmp[b - 1];
    int mycnt = cursor[b];

    for (int k = tid; k < mycnt; k += 256) stg[k] = region[b * BCAP + k];
    lc[tid] = 0;
    __syncthreads();

    int node0 = b << 8;
    for (int k = tid; k < mycnt; k += 256) {
        int local = (int)(stg[k] >> 16) - node0;
        atomicAdd(&lc[local], 1);
    }
    __syncthreads();

    int myc = lc[tid];
    sctmp[tid] = myc;
    __syncthreads();
    for (int off = 1; off < 256; off <<= 1) {
        int t = (tid >= off) ? sctmp[tid - off] : 0;
        __syncthreads();
        sctmp[tid] += t;
        __syncthreads();
    }
    int myoff = sctmp[tid] - myc;
    cur[tid] = myoff;
    int n = node0 + tid;
    if (n < NN) {
        deg_i[n] = myc;
        base[n] = B0 + myoff + myc;   // row_end (gather contract)
    }
    __syncthreads();

    for (int k = tid; k < mycnt; k += 256) {
        unsigned int p = stg[k];
        int local = (int)(p >> 16) - node0;
        int pos = atomicAdd(&cur[local], 1);
        csr16[B0 + pos] = (unsigned short)(p & 0xffffu);
    }
}

// ---------------- gather aggregation, 32 channels (x fp32) ----------------
// 32 lanes per node: 4 edge-slots x 8 channel-lanes (4 ch each).
__global__ __launch_bounds__(256) void k_gather32(const unsigned short* __restrict__ csr_src,
                                                  const int* __restrict__ base,
                                                  const int* __restrict__ deg_i,
                                                  const float* __restrict__ x,
                                                  float* __restrict__ agg) {
    int t = blockIdx.x * 256 + threadIdx.x;
    int n = t >> 5;
    if (n >= NN) return;
    int p = (t >> 3) & 3;            // edge slot 0..3
    int c4 = (t & 7) << 2;           // channel offset
    int end = base[n];
    int st = end - deg_i[n];
    float4 acc = make_float4(0.f, 0.f, 0.f, 0.f);
    for (int e = st + p; e < end; e += 4) {
        int s = csr_src[e];
        float4 v = *(const float4*)(x + (size_t)s * 32 + c4);
        acc.x += v.x; acc.y += v.y; acc.z += v.z; acc.w += v.w;
    }
    acc.x += __shfl_xor(acc.x, 8, 64);
    acc.y += __shfl_xor(acc.y, 8, 64);
    acc.z += __shfl_xor(acc.z, 8, 64);
    acc.w += __shfl_xor(acc.w, 8, 64);
    acc.x += __shfl_xor(acc.x, 16, 64);
    acc.y += __shfl_xor(acc.y, 16, 64);
    acc.z += __shfl_xor(acc.z, 16, 64);
    acc.w += __shfl_xor(acc.w, 16, 64);
    if (p == 0) *(float4*)(agg + (size_t)n * 32 + c4) = acc;
}

// ---------------- gather aggregation, 64 channels (h bf16) ----------------
// 64 lanes (full wave) per node: 4 edge-slots x 16 channel-lanes (4 ch each).
// Per edge: 16 lanes x uint2 (8B = 4 bf16) = 128B coalesced row read.
__global__ __launch_bounds__(256) void k_gather64(const unsigned short* __restrict__ csr_src,
                                                  const int* __restrict__ base,
                                                  const int* __restrict__ deg_i,
                                                  const unsigned short* __restrict__ h,
                                                  float* __restrict__ agg) {
    int t = blockIdx.x * 256 + threadIdx.x;
    int n = t >> 6;
    if (n >= NN) return;
    int p = (t >> 4) & 3;            // edge slot 0..3
    int c4 = (t & 15) << 2;          // channel offset
    int end = base[n];
    int st = end - deg_i[n];
    float4 acc = make_float4(0.f, 0.f, 0.f, 0.f);
    for (int e = st + p; e < end; e += 4) {
        int s = csr_src[e];
        uint2 v = *(const uint2*)(h + (size_t)s * 64 + c4);
        acc.x += __uint_as_float(v.x << 16);
        acc.y += __uint_as_float(v.x & 0xffff0000u);
        acc.z += __uint_as_float(v.y << 16);
        acc.w += __uint_as_float(v.y & 0xffff0000u);
    }
    acc.x += __shfl_xor(acc.x, 16, 64);
    acc.y += __shfl_xor(acc.y, 16, 64);
    acc.z += __shfl_xor(acc.z, 16, 64);
    acc.w += __shfl_xor(acc.w, 16, 64);
    acc.x += __shfl_xor(acc.x, 32, 64);
    acc.y += __shfl_xor(acc.y, 32, 64);
    acc.z += __shfl_xor(acc.z, 32, 64);
    acc.w += __shfl_xor(acc.w, 32, 64);
    if (p == 0) *(float4*)(agg + (size_t)n * 64 + c4) = acc;
}

// ---------------- node update layer 1 -> h (bf16) ----------------
// h = relu(bn1(agg*deg_inv @ W1l + b1l + x @ W1r))
// Block = 64 nodes. W1l|W1r staged in LDS (16KB). 16 lanes per node x 4
// out-ch per lane; 4 nodes per thread. unroll capped at 4 (r4 spill lesson).
__global__ __launch_bounds__(256) void k_node1(
    const float* __restrict__ x, const float* __restrict__ agg,
    const int* __restrict__ deg_i,
    const float* __restrict__ W1l, const float* __restrict__ b1l,
    const float* __restrict__ W1r,
    const float* __restrict__ g1, const float* __restrict__ bb1,
    const float* __restrict__ m1, const float* __restrict__ v1,
    unsigned short* __restrict__ h) {
    __shared__ float wlds[32 * 128];
    int tid = threadIdx.x;
    {
        const float4* l4 = (const float4*)W1l;   // 512 float4
        const float4* r4 = (const float4*)W1r;
        float4* s4 = (float4*)wlds;
#pragma unroll
        for (int i = 0; i < 2; i++) {
            int idx = tid + i * 256;
            int k = idx >> 4, c = idx & 15;
            s4[k * 32 + c] = l4[idx];
            s4[k * 32 + 16 + c] = r4[idx];
        }
    }
    __syncthreads();

    int lg = tid & 15, o4 = lg << 2;
    int nbase = blockIdx.x * 64 + (tid >> 4) * 4;
    if (nbase >= NN) return;

    float4 acc[4];
    float di[4];
    int nj[4];
#pragma unroll
    for (int j = 0; j < 4; j++) {
        acc[j] = make_float4(0.f, 0.f, 0.f, 0.f);
        nj[j] = min(nbase + j, NN - 1);   // clamp: loads stay in-bounds
        di[j] = 1.0f / fmaxf((float)deg_i[nj[j]], 1.0f);
    }

#pragma unroll 4
    for (int i4 = 0; i4 < 32; i4 += 4) {
        float4 wl[4], wr[4];
#pragma unroll
        for (int k = 0; k < 4; k++) {
            wl[k] = *(const float4*)&wlds[(i4 + k) * 128 + o4];
            wr[k] = *(const float4*)&wlds[(i4 + k) * 128 + 64 + o4];
        }
#pragma unroll
        for (int j = 0; j < 4; j++) {
            float4 a4 = *(const float4*)(agg + (size_t)nj[j] * 32 + i4);
            float4 x4 = *(const float4*)(x + (size_t)nj[j] * 32 + i4);
            float av[4] = {a4.x * di[j], a4.y * di[j], a4.z * di[j], a4.w * di[j]};
            float xv[4] = {x4.x, x4.y, x4.z, x4.w};
#pragma unroll
            for (int k = 0; k < 4; k++) {
                acc[j].x += av[k] * wl[k].x + xv[k] * wr[k].x;
                acc[j].y += av[k] * wl[k].y + xv[k] * wr[k].y;
                acc[j].z += av[k] * wl[k].z + xv[k] * wr[k].z;
                acc[j].w += av[k] * wl[k].w + xv[k] * wr[k].w;
            }
        }
    }

    float4 bl = *(const float4*)(b1l + o4);
    float4 gg = *(const float4*)(g1 + o4);
    float4 bb = *(const float4*)(bb1 + o4);
    float4 mm = *(const float4*)(m1 + o4);
    float4 vv = *(const float4*)(v1 + o4);
    float4 sc;
    sc.x = gg.x * rsqrtf(vv.x + BN_EPS);
    sc.y = gg.y * rsqrtf(vv.y + BN_EPS);
    sc.z = gg.z * rsqrtf(vv.z + BN_EPS);
    sc.w = gg.w * rsqrtf(vv.w + BN_EPS);
#pragma unroll
    for (int j = 0; j < 4; j++) {
        if (nbase + j >= NN) break;
        ushort4 r;
        r.x = f2bf(fmaxf((acc[j].x + bl.x - mm.x) * sc.x + bb.x, 0.0f));
        r.y = f2bf(fmaxf((acc[j].y + bl.y - mm.y) * sc.y + bb.y, 0.0f));
        r.z = f2bf(fmaxf((acc[j].z + bl.z - mm.z) * sc.z + bb.z, 0.0f));
        r.w = f2bf(fmaxf((acc[j].w + bl.w - mm.w) * sc.w + bb.w, 0.0f));
        *(ushort4*)(h + (size_t)(nbase + j) * 64 + o4) = r;
    }
}

// ---------------- node update layer 2 + final linear ----------------
// out = relu(bn2(agg*deg_inv @ W2l + b2l + h @ W2r)) @ Wlin + blin
// h roots read as bf16 (uint2 per 4 channels).
__global__ __launch_bounds__(256) void k_node2(
    const unsigned short* __restrict__ h, const float* __restrict__ agg,
    const int* __restrict__ deg_i,
    const float* __restrict__ W2l, const float* __restrict__ b2l,
    const float* __restrict__ W2r,
    const float* __restrict__ g2, const float* __restrict__ bb2,
    const float* __restrict__ m2, const float* __restrict__ v2,
    const float* __restrict__ Wlin, const float* __restrict__ blin,
    float* __restrict__ out) {
    __shared__ float wlds[64 * 128];
    int tid = threadIdx.x;
    {
        const float4* l4 = (const float4*)W2l;   // 1024 float4
        const float4* r4 = (const float4*)W2r;
        float4* s4 = (float4*)wlds;
#pragma unroll
        for (int i = 0; i < 4; i++) {
            int idx = tid + i * 256;
            int k = idx >> 4, c = idx & 15;
            s4[k * 32 + c] = l4[idx];
            s4[k * 32 + 16 + c] = r4[idx];
        }
    }
    __syncthreads();

    int lg = tid & 15, o4 = lg << 2;
    int nbase = blockIdx.x * 64 + (tid >> 4) * 4;
    if (nbase >= NN) return;

    float4 acc[4];
    float di[4];
    int nj[4];
#pragma unroll
    for (int j = 0; j < 4; j++) {
        acc[j] = make_float4(0.f, 0.f, 0.f, 0.f);
        nj[j] = min(nbase + j, NN - 1);
        di[j] = 1.0f / fmaxf((float)deg_i[nj[j]], 1.0f);
    }

#pragma unroll 4
    for (int i4 = 0; i4 < 64; i4 += 4) {
        float4 wl[4], wr[4];
#pragma unroll
        for (int k = 0; k < 4; k++) {
            wl[k] = *(const float4*)&wlds[(i4 + k) * 128 + o4];
            wr[k] = *(const float4*)&wlds[(i4 + k) * 128 + 64 + o4];
        }
#pragma unroll
        for (int j = 0; j < 4; j++) {
            float4 a4 = *(const float4*)(agg + (size_t)nj[j] * 64 + i4);
            uint2 hu = *(const uint2*)(h + (size_t)nj[j] * 64 + i4);
            float av[4] = {a4.x * di[j], a4.y * di[j], a4.z * di[j], a4.w * di[j]};
            float hv[4];
            hv[0] = __uint_as_float(hu.x << 16);
            hv[1] = __uint_as_float(hu.x & 0xffff0000u);
            hv[2] = __uint_as_float(hu.y << 16);
            hv[3] = __uint_as_float(hu.y & 0xffff0000u);
#pragma unroll
            for (int k = 0; k < 4; k++) {
                acc[j].x += av[k] * wl[k].x + hv[k] * wr[k].x;
                acc[j].y += av[k] * wl[k].y + hv[k] * wr[k].y;
                acc[j].z += av[k] * wl[k].z + hv[k] * wr[k].z;
                acc[j].w += av[k] * wl[k].w + hv[k] * wr[k].w;
            }
        }
    }

    float4 bl = *(const float4*)(b2l + o4);
    float4 gg = *(const float4*)(g2 + o4);
    float4 bb = *(const float4*)(bb2 + o4);
    float4 mm = *(const float4*)(m2 + o4);
    float4 vv = *(const float4*)(v2 + o4);
    float4 wo = *(const float4*)(Wlin + o4);
    float blin0 = blin[0];
    float4 sc;
    sc.x = gg.x * rsqrtf(vv.x + BN_EPS);
    sc.y = gg.y * rsqrtf(vv.y + BN_EPS);
    sc.z = gg.z * rsqrtf(vv.z + BN_EPS);
    sc.w = gg.w * rsqrtf(vv.w + BN_EPS);
#pragma unroll
    for (int j = 0; j < 4; j++) {
        float vx = fmaxf((acc[j].x + bl.x - mm.x) * sc.x + bb.x, 0.0f);
        float vy = fmaxf((acc[j].y + bl.y - mm.y) * sc.y + bb.y, 0.0f);
        float vz = fmaxf((acc[j].z + bl.z - mm.z) * sc.z + bb.z, 0.0f);
        float vw = fmaxf((acc[j].w + bl.w - mm.w) * sc.w + bb.w, 0.0f);
        float part = vx * wo.x + vy * wo.y + vz * wo.z + vw * wo.w;
#pragma unroll
        for (int m = 1; m < 16; m <<= 1) part += __shfl_xor(part, m, 64);
        if (lg == 0 && nbase + j < NN) out[nbase + j] = part + blin0;
    }
}

extern "C" void kernel_launch(void* const* d_in, const int* in_sizes, int n_in,
                              void* d_out, int out_size, void* d_ws, size_t ws_size,
                              hipStream_t stream) {
    const float* x    = (const float*)d_in[0];
    const int*   ei   = (const int*)d_in[1];
    const float* W1l  = (const float*)d_in[2];
    const float* b1l  = (const float*)d_in[3];
    const float* W1r  = (const float*)d_in[4];
    const float* g1   = (const float*)d_in[5];
    const float* bb1  = (const float*)d_in[6];
    const float* m1   = (const float*)d_in[7];
    const float* v1   = (const float*)d_in[8];
    const float* W2l  = (const float*)d_in[9];
    const float* b2l  = (const float*)d_in[10];
    const float* W2r  = (const float*)d_in[11];
    const float* g2   = (const float*)d_in[12];
    const float* bb2  = (const float*)d_in[13];
    const float* m2   = (const float*)d_in[14];
    const float* v2   = (const float*)d_in[15];
    const float* Wlin = (const float*)d_in[16];
    const float* blin = (const float*)d_in[17];
    float* out = (float*)d_out;

    // ws layout:
    //   cursor  int[256]          per-bucket claim cursors (only [0,196) used)
    //   region  u32[196*8192]     binned packed edges (6.4MB)
    //   deg_i   int[N]            degree per dst node (written by pass B)
    //   base    int[N]            row_end per node (written by pass B)
    //   csr16   ushort[E]         src indices sorted by dst
    //   agg     float[64N]        aggregation buffer (reused both layers)
    //   h       bf16[64N]         layer-1 output (6.4MB)
    int* cursor = (int*)d_ws;
    unsigned int* region = (unsigned int*)(cursor + 256);
    int* deg_i = (int*)(region + (size_t)NBUCK * BCAP);
    int* base  = deg_i + NN;
    unsigned short* csr16 = (unsigned short*)(base + NN);
    float* agg = (float*)(csr16 + NE);
    unsigned short* h = (unsigned short*)(agg + (size_t)64 * NN);

    // only the bucket cursors need zeroing (1KB)
    hipMemsetAsync(cursor, 0, 256 * sizeof(int), stream);

    k_binA<<<NAB, 256, 0, stream>>>(ei, cursor, region);
    k_binB<<<NBUCK, 256, 0, stream>>>(cursor, region, deg_i, base, csr16);

    k_gather32<<<(NN * 32 + 255) / 256, 256, 0, stream>>>(csr16, base, deg_i, x, agg);
    k_node1<<<NBLK, 256, 0, stream>>>(x, agg, deg_i, W1l, b1l, W1r,
                                      g1, bb1, m1, v1, h);
    k_gather64<<<(NN * 64 + 255) / 256, 256, 0, stream>>>(csr16, base, deg_i, h, agg);
    k_node2<<<NBLK, 256, 0, stream>>>(h, agg, deg_i, W2l, b2l, W2r,
                                      g2, bb2, m2, v2, Wlin, blin, out);
}